// Round 2
// baseline (492.285 us; speedup 1.0000x reference)
//
#include <hip/hip_runtime.h>
#include <hip/hip_bf16.h>

#define NN   10000
#define BB   4
#define DD   128
#define HIDD 256
#define NEG  0.2f
#define CHUNK 512

using bf16 = __hip_bfloat16;
typedef __bf16 bf16x8 __attribute__((ext_vector_type(8)));
typedef float  f32x4  __attribute__((ext_vector_type(4)));

__device__ __forceinline__ float b2f(bf16 v) { return __bfloat162float(v); }
__device__ __forceinline__ void store_out(bf16* p, float v) { *p = __float2bfloat16(v); }
__device__ __forceinline__ void store_out(float* p, float v) { *p = v; }

// ---------------- fp32 -> bf16 conversions ----------------
__global__ void convert_kernel(const float* __restrict__ x, bf16* __restrict__ y, int n) {
    int i = blockIdx.x * 256 + threadIdx.x;
    if (i < n) y[i] = __float2bfloat16(x[i]);
}

// Wt[n][k] = bf16(W[k][n])
__global__ void convwt_kernel(const float* __restrict__ W, bf16* __restrict__ Wt, int K) {
    int idx = blockIdx.x * 256 + threadIdx.x;
    if (idx < K * HIDD) {
        int k = idx / HIDD, n = idx % HIDD;
        Wt[(size_t)n * K + k] = __float2bfloat16(W[idx]);
    }
}

// ---------------- CSR build ----------------
__global__ void zero_kernel(int* p, int n) {
    int i = blockIdx.x * 256 + threadIdx.x;
    if (i < n) p[i] = 0;
}

__global__ void hist_kernel(const int* __restrict__ dstv, int* counts, int E) {
    int e = blockIdx.x * 256 + threadIdx.x;
    if (e < E) atomicAdd(&counts[dstv[e]], 1);
}

__global__ __launch_bounds__(1024) void scan_kernel(const int* __restrict__ counts,
                                                    int* row_start, int* cursor) {
    __shared__ int part[1024];
    int t = threadIdx.x;
    const int CH = (NN + 1023) / 1024;  // 10
    int base = t * CH;
    int s = 0;
    for (int j = 0; j < CH; j++) { int idx = base + j; if (idx < NN) s += counts[idx]; }
    part[t] = s;
    __syncthreads();
    for (int off = 1; off < 1024; off <<= 1) {
        int v = (t >= off) ? part[t - off] : 0;
        __syncthreads();
        part[t] += v;
        __syncthreads();
    }
    int excl = (t == 0) ? 0 : part[t - 1];
    for (int j = 0; j < CH; j++) {
        int idx = base + j;
        if (idx < NN) { row_start[idx] = excl; cursor[idx] = excl; excl += counts[idx]; }
    }
    if (t == 1023) row_start[NN] = part[1023];
}

__global__ void scatter_kernel(const int* __restrict__ srcv, const int* __restrict__ dstv,
                               int* cursor, int* csr_src, int E) {
    int e = blockIdx.x * 256 + threadIdx.x;
    if (e < E) {
        int d = dstv[e];
        int p = atomicAdd(&cursor[d], 1);
        csr_src[p] = srcv[e];
    }
}

// ---------------- GEMM: H[g] = A[g] @ W  (A: [M,K] bf16, Wt: [256,K] bf16) ----------------
// per wave: 16 rows x 64 cols via 4 x mfma_f32_16x16x32_bf16, direct global->reg loads
template <int K>
__global__ __launch_bounds__(256) void gemm_kernel(const bf16* __restrict__ A,
                                                   const bf16* __restrict__ Wt,
                                                   bf16* __restrict__ H) {
    const int M = NN;
    int g    = blockIdx.z;
    int wave = threadIdx.x >> 6, lane = threadIdx.x & 63;
    int m0   = blockIdx.x * 64 + wave * 16;
    int n0   = blockIdx.y * 64;
    int lm   = lane & 15, lq = lane >> 4;

    int row = m0 + lm;
    if (row > M - 1) row = M - 1;  // clamp (stores guarded)
    const bf16* Arow = A + ((size_t)g * M + row) * K + lq * 8;

    f32x4 acc[4];
#pragma unroll
    for (int i = 0; i < 4; i++) acc[i] = (f32x4){0.f, 0.f, 0.f, 0.f};

#pragma unroll
    for (int k0 = 0; k0 < K; k0 += 32) {
        bf16x8 av = *(const bf16x8*)(Arow + k0);
#pragma unroll
        for (int fi = 0; fi < 4; fi++) {
            const bf16* Bp = Wt + (size_t)(n0 + fi * 16 + lm) * K + lq * 8 + k0;
            bf16x8 bv = *(const bf16x8*)Bp;
            acc[fi] = __builtin_amdgcn_mfma_f32_16x16x32_bf16(av, bv, acc[fi], 0, 0, 0);
        }
    }

    int crow0 = m0 + lq * 4;
#pragma unroll
    for (int fi = 0; fi < 4; fi++) {
        int col = n0 + fi * 16 + lm;
#pragma unroll
        for (int r = 0; r < 4; r++) {
            int cr = crow0 + r;
            if (cr < M)
                H[((size_t)g * M + cr) * HIDD + col] = __float2bfloat16(acc[fi][r]);
        }
    }
}

// ---------------- attention coefficients: al_s/al_d [B*N][2] fp32 ----------------
__global__ __launch_bounds__(256) void al_kernel(const bf16* __restrict__ H,
                                                 const float* __restrict__ a_src,
                                                 const float* __restrict__ a_dst,
                                                 float* __restrict__ als,
                                                 float* __restrict__ ald) {
    int gn = blockIdx.x;
    int t = threadIdx.x, lane = t & 63, wave = t >> 6;
    float v  = b2f(H[(size_t)gn * HIDD + t]);
    float ps = v * a_src[t];   // a_src flat [hd*128+f] == t
    float pd = v * a_dst[t];
#pragma unroll
    for (int off = 32; off; off >>= 1) {
        ps += __shfl_down(ps, off);
        pd += __shfl_down(pd, off);
    }
    __shared__ float sps[4], spd[4];
    if (lane == 0) { sps[wave] = ps; spd[wave] = pd; }
    __syncthreads();
    if (t == 0)   { als[(size_t)gn * 2 + 0] = sps[0] + sps[1]; ald[(size_t)gn * 2 + 0] = spd[0] + spd[1]; }
    if (t == 128) { als[(size_t)gn * 2 + 1] = sps[2] + sps[3]; ald[(size_t)gn * 2 + 1] = spd[2] + spd[3]; }
}

// ---------------- softmax + aggregate + bias + LN + ReLU, one block per (g,n) ----------------
template <typename OT>
__global__ __launch_bounds__(256) void node_kernel(const int* __restrict__ row_start,
                                                   const int* __restrict__ csr_src,
                                                   const float* __restrict__ als_all,
                                                   const float* __restrict__ ald_all,
                                                   const bf16* __restrict__ H,
                                                   const float* __restrict__ bias,
                                                   const float* __restrict__ gam,
                                                   const float* __restrict__ bet,
                                                   OT* __restrict__ out) {
    int gn = blockIdx.x;
    int g  = gn / NN;
    int n  = gn - g * NN;
    int t = threadIdx.x, lane = t & 63, wave = t >> 6, hd = t >> 7;
    int start = row_start[n];
    int deg   = row_start[n + 1] - start;

    __shared__ float s_m[2], s_d[2];
    __shared__ int   s_src[CHUNK];
    __shared__ float s_w[2][CHUNK];

    const float* als = als_all + (size_t)g * NN * 2;
    float ad0 = 0.f, ad1 = 0.f, mm0 = -1e30f, mm1 = -1e30f;

    if (wave == 0) {
        ad0 = ald_all[((size_t)g * NN + n) * 2 + 0];
        ad1 = ald_all[((size_t)g * NN + n) * 2 + 1];
        float m0 = -1e30f, m1 = -1e30f;
        for (int i = lane; i < deg; i += 64) {
            int s = csr_src[start + i];
            float x0 = als[(size_t)s * 2 + 0] + ad0; x0 = x0 > 0.f ? x0 : NEG * x0;
            float x1 = als[(size_t)s * 2 + 1] + ad1; x1 = x1 > 0.f ? x1 : NEG * x1;
            m0 = fmaxf(m0, x0); m1 = fmaxf(m1, x1);
        }
#pragma unroll
        for (int off = 32; off; off >>= 1) {
            m0 = fmaxf(m0, __shfl_xor(m0, off));
            m1 = fmaxf(m1, __shfl_xor(m1, off));
        }
        float d0 = 0.f, d1 = 0.f;
        for (int i = lane; i < deg; i += 64) {
            int s = csr_src[start + i];
            float x0 = als[(size_t)s * 2 + 0] + ad0; x0 = x0 > 0.f ? x0 : NEG * x0;
            float x1 = als[(size_t)s * 2 + 1] + ad1; x1 = x1 > 0.f ? x1 : NEG * x1;
            d0 += __expf(x0 - m0); d1 += __expf(x1 - m1);
        }
#pragma unroll
        for (int off = 32; off; off >>= 1) {
            d0 += __shfl_xor(d0, off);
            d1 += __shfl_xor(d1, off);
        }
        if (lane == 0) { s_m[0] = m0; s_m[1] = m1; s_d[0] = d0; s_d[1] = d1; }
        mm0 = m0; mm1 = m1;
    }
    __syncthreads();

    const bf16* Hg = H + (size_t)g * NN * HIDD;
    float acc = 0.f;
    for (int c0 = 0; c0 < deg; c0 += CHUNK) {
        int cn = min(CHUNK, deg - c0);
        if (wave == 0) {
            for (int i = lane; i < cn; i += 64) {
                int s = csr_src[start + c0 + i];
                s_src[i] = s;
                float x0 = als[(size_t)s * 2 + 0] + ad0; x0 = x0 > 0.f ? x0 : NEG * x0;
                float x1 = als[(size_t)s * 2 + 1] + ad1; x1 = x1 > 0.f ? x1 : NEG * x1;
                s_w[0][i] = __expf(x0 - mm0);
                s_w[1][i] = __expf(x1 - mm1);
            }
        }
        __syncthreads();
        for (int i = 0; i < cn; i++) {
            acc += s_w[hd][i] * b2f(Hg[(size_t)s_src[i] * HIDD + t]);
        }
        __syncthreads();
    }

    float v = acc / s_d[hd] + bias[t];

    // LayerNorm over 256 channels (block-wide)
    float s1 = v, s2 = v * v;
#pragma unroll
    for (int off = 32; off; off >>= 1) {
        s1 += __shfl_xor(s1, off);
        s2 += __shfl_xor(s2, off);
    }
    __shared__ float r1[4], r2[4];
    if (lane == 0) { r1[wave] = s1; r2[wave] = s2; }
    __syncthreads();
    float sum = r1[0] + r1[1] + r1[2] + r1[3];
    float sq  = r2[0] + r2[1] + r2[2] + r2[3];
    float mu  = sum * (1.f / HIDD);
    float var = sq * (1.f / HIDD) - mu * mu;
    float o = (v - mu) * rsqrtf(var + 1e-5f) * gam[t] + bet[t];
    o = fmaxf(o, 0.f);
    store_out(&out[(size_t)gn * HIDD + t], o);
}

// ---------------- launch ----------------
extern "C" void kernel_launch(void* const* d_in, const int* in_sizes, int n_in,
                              void* d_out, int out_size, void* d_ws, size_t ws_size,
                              hipStream_t stream) {
    const float* feature = (const float*)d_in[0];
    const int*   ei      = (const int*)d_in[1];
    const float* W1      = (const float*)d_in[2];
    const float* a_src1  = (const float*)d_in[3];
    const float* a_dst1  = (const float*)d_in[4];
    const float* b1      = (const float*)d_in[5];
    const float* g1      = (const float*)d_in[6];
    const float* be1     = (const float*)d_in[7];
    const float* W2      = (const float*)d_in[8];
    const float* a_src2  = (const float*)d_in[9];
    const float* a_dst2  = (const float*)d_in[10];
    const float* b2      = (const float*)d_in[11];
    const float* g2      = (const float*)d_in[12];
    const float* be2     = (const float*)d_in[13];
    float* out = (float*)d_out;

    const int E = in_sizes[1] / 2;
    const int* srcv = ei;
    const int* dstv = ei + E;

    char* w = (char*)d_ws;
    auto alloc = [&](size_t bytes) -> char* {
        char* p = w;
        w += (bytes + 255) & ~(size_t)255;
        return p;
    };
    int*   counts    = (int*)alloc(sizeof(int) * NN);
    int*   row_start = (int*)alloc(sizeof(int) * (NN + 1));
    int*   cursor    = (int*)alloc(sizeof(int) * NN);
    int*   csr_src   = (int*)alloc(sizeof(int) * E);
    float* als       = (float*)alloc(sizeof(float) * (size_t)BB * NN * 2);
    float* ald       = (float*)alloc(sizeof(float) * (size_t)BB * NN * 2);
    bf16*  featbf    = (bf16*)alloc(sizeof(bf16) * (size_t)BB * NN * DD);
    bf16*  h         = (bf16*)alloc(sizeof(bf16) * (size_t)BB * NN * HIDD);
    bf16*  x2        = (bf16*)alloc(sizeof(bf16) * (size_t)BB * NN * HIDD);
    bf16*  Wt        = (bf16*)alloc(sizeof(bf16) * HIDD * HIDD);

    // CSR build (shared by both layers, all graphs)
    zero_kernel<<<(NN + 255) / 256, 256, 0, stream>>>(counts, NN);
    hist_kernel<<<(E + 255) / 256, 256, 0, stream>>>(dstv, counts, E);
    scan_kernel<<<1, 1024, 0, stream>>>(counts, row_start, cursor);
    scatter_kernel<<<(E + 255) / 256, 256, 0, stream>>>(srcv, dstv, cursor, csr_src, E);

    // Layer 1
    {
        int nf = BB * NN * DD;
        convert_kernel<<<(nf + 255) / 256, 256, 0, stream>>>(feature, featbf, nf);
    }
    convwt_kernel<<<(DD * HIDD + 255) / 256, 256, 0, stream>>>(W1, Wt, DD);
    gemm_kernel<DD><<<dim3((NN + 63) / 64, HIDD / 64, BB), 256, 0, stream>>>(featbf, Wt, h);
    al_kernel<<<BB * NN, 256, 0, stream>>>(h, a_src1, a_dst1, als, ald);
    node_kernel<bf16><<<BB * NN, 256, 0, stream>>>(row_start, csr_src, als, ald, h, b1, g1, be1, x2);

    // Layer 2
    convwt_kernel<<<(HIDD * HIDD + 255) / 256, 256, 0, stream>>>(W2, Wt, HIDD);
    gemm_kernel<HIDD><<<dim3((NN + 63) / 64, HIDD / 64, BB), 256, 0, stream>>>(x2, Wt, h);
    al_kernel<<<BB * NN, 256, 0, stream>>>(h, a_src2, a_dst2, als, ald);
    node_kernel<float><<<BB * NN, 256, 0, stream>>>(row_start, csr_src, als, ald, h, b2, g2, be2, out);
}

// Round 3
// 444.319 us; speedup vs baseline: 1.1080x; 1.1080x over previous
//
#include <hip/hip_runtime.h>
#include <hip/hip_bf16.h>

#define NN   10000
#define BB   4
#define DD   128
#define HIDD 256
#define NEG  0.2f
#define CHUNK 512

using bf16 = __hip_bfloat16;
typedef __bf16 bf16x8 __attribute__((ext_vector_type(8)));
typedef float  f32x4  __attribute__((ext_vector_type(4)));

__device__ __forceinline__ float b2f(bf16 v) { return __bfloat162float(v); }
__device__ __forceinline__ void store_out(bf16* p, float v) { *p = __float2bfloat16(v); }
__device__ __forceinline__ void store_out(float* p, float v) { *p = v; }

// ---------------- fp32 -> bf16 conversions ----------------
__global__ void convert_kernel(const float* __restrict__ x, bf16* __restrict__ y, int n) {
    int i = blockIdx.x * 256 + threadIdx.x;
    if (i < n) y[i] = __float2bfloat16(x[i]);
}

// Wt[n][k] = bf16(W[k][n])
__global__ void convwt_kernel(const float* __restrict__ W, bf16* __restrict__ Wt, int K) {
    int idx = blockIdx.x * 256 + threadIdx.x;
    if (idx < K * HIDD) {
        int k = idx / HIDD, n = idx % HIDD;
        Wt[(size_t)n * K + k] = __float2bfloat16(W[idx]);
    }
}

// ---------------- CSR build ----------------
__global__ void zero_kernel(int* p, int n) {
    int i = blockIdx.x * 256 + threadIdx.x;
    if (i < n) p[i] = 0;
}

__global__ void hist_kernel(const int* __restrict__ dstv, int* counts, int E) {
    int e = blockIdx.x * 256 + threadIdx.x;
    if (e < E) atomicAdd(&counts[dstv[e]], 1);
}

__global__ __launch_bounds__(1024) void scan_kernel(const int* __restrict__ counts,
                                                    int* row_start, int* cursor) {
    __shared__ int part[1024];
    int t = threadIdx.x;
    const int CH = (NN + 1023) / 1024;  // 10
    int base = t * CH;
    int s = 0;
    for (int j = 0; j < CH; j++) { int idx = base + j; if (idx < NN) s += counts[idx]; }
    part[t] = s;
    __syncthreads();
    for (int off = 1; off < 1024; off <<= 1) {
        int v = (t >= off) ? part[t - off] : 0;
        __syncthreads();
        part[t] += v;
        __syncthreads();
    }
    int excl = (t == 0) ? 0 : part[t - 1];
    for (int j = 0; j < CH; j++) {
        int idx = base + j;
        if (idx < NN) { row_start[idx] = excl; cursor[idx] = excl; excl += counts[idx]; }
    }
    if (t == 1023) row_start[NN] = part[1023];
}

__global__ void scatter_kernel(const int* __restrict__ srcv, const int* __restrict__ dstv,
                               int* cursor, int* csr_src, int E) {
    int e = blockIdx.x * 256 + threadIdx.x;
    if (e < E) {
        int d = dstv[e];
        int p = atomicAdd(&cursor[d], 1);
        csr_src[p] = srcv[e];
    }
}

// ---------------- GEMM + fused attention coefficients ----------------
// wave: 16 rows x 256 cols via 16 x mfma_f32_16x16x32_bf16; epilogue computes
// al_s/al_d per (row, head) in fp32 via in-wave shfl reduction over 16 col-lanes.
template <int K>
__global__ __launch_bounds__(256) void gemm_kernel(const bf16* __restrict__ A,
                                                   const bf16* __restrict__ Wt,
                                                   const float* __restrict__ a_src,
                                                   const float* __restrict__ a_dst,
                                                   bf16* __restrict__ H,
                                                   float* __restrict__ als,
                                                   float* __restrict__ ald) {
    int g    = blockIdx.y;
    int wave = threadIdx.x >> 6, lane = threadIdx.x & 63;
    int m0   = blockIdx.x * 64 + wave * 16;
    int lm   = lane & 15, lq = lane >> 4;

    int row = m0 + lm;
    if (row > NN - 1) row = NN - 1;  // clamp (stores guarded)
    const bf16* Arow = A + ((size_t)g * NN + row) * K + lq * 8;

    f32x4 acc[16];
#pragma unroll
    for (int i = 0; i < 16; i++) acc[i] = (f32x4){0.f, 0.f, 0.f, 0.f};

#pragma unroll
    for (int k0 = 0; k0 < K; k0 += 32) {
        bf16x8 av = *(const bf16x8*)(Arow + k0);
#pragma unroll
        for (int fi = 0; fi < 16; fi++) {
            const bf16* Bp = Wt + (size_t)(fi * 16 + lm) * K + lq * 8 + k0;
            bf16x8 bv = *(const bf16x8*)Bp;
            acc[fi] = __builtin_amdgcn_mfma_f32_16x16x32_bf16(av, bv, acc[fi], 0, 0, 0);
        }
    }

    int crow0 = m0 + lq * 4;
    float ps[2][4] = {{0.f, 0.f, 0.f, 0.f}, {0.f, 0.f, 0.f, 0.f}};
    float pd[2][4] = {{0.f, 0.f, 0.f, 0.f}, {0.f, 0.f, 0.f, 0.f}};

#pragma unroll
    for (int fi = 0; fi < 16; fi++) {
        int col = fi * 16 + lm;
        float as = a_src[col], ad = a_dst[col];
        int h = fi >> 3;
#pragma unroll
        for (int r = 0; r < 4; r++) {
            float v = acc[fi][r];
            ps[h][r] = fmaf(v, as, ps[h][r]);
            pd[h][r] = fmaf(v, ad, pd[h][r]);
            int cr = crow0 + r;
            if (cr < NN)
                H[((size_t)g * NN + cr) * HIDD + col] = __float2bfloat16(v);
        }
    }

#pragma unroll
    for (int h = 0; h < 2; h++) {
#pragma unroll
        for (int r = 0; r < 4; r++) {
            float a = ps[h][r], b = pd[h][r];
#pragma unroll
            for (int off = 1; off < 16; off <<= 1) {
                a += __shfl_xor(a, off);
                b += __shfl_xor(b, off);
            }
            if (lm == 0) {
                int cr = crow0 + r;
                if (cr < NN) {
                    als[((size_t)g * NN + cr) * 2 + h] = a;
                    ald[((size_t)g * NN + cr) * 2 + h] = b;
                }
            }
        }
    }
}

// ---------------- softmax + aggregate + bias + LN + ReLU, one block per (g,n) ----------------
// aggregation: 8 edge-groups x 32 threads; each thread owns 8 contiguous channels (uint4 load)
template <typename OT>
__global__ __launch_bounds__(256) void node_kernel(const int* __restrict__ row_start,
                                                   const int* __restrict__ csr_src,
                                                   const float* __restrict__ als_all,
                                                   const float* __restrict__ ald_all,
                                                   const bf16* __restrict__ H,
                                                   const float* __restrict__ bias,
                                                   const float* __restrict__ gam,
                                                   const float* __restrict__ bet,
                                                   OT* __restrict__ out) {
    int gn = blockIdx.x;
    int g  = gn / NN;
    int n  = gn - g * NN;
    int t = threadIdx.x, lane = t & 63, wave = t >> 6;
    int grp = t >> 5, lch = t & 31;
    int hd_g = lch >> 4;  // head of this thread's 8 channels
    int start = row_start[n];
    int deg   = row_start[n + 1] - start;

    __shared__ float s_d[2];
    __shared__ int   s_src[CHUNK];
    __shared__ float s_w[2][CHUNK];
    __shared__ float s_acc[8][256];

    const float* als = als_all + (size_t)g * NN * 2;
    float ad0 = 0.f, ad1 = 0.f, mm0 = -1e30f, mm1 = -1e30f;

    if (wave == 0) {
        ad0 = ald_all[((size_t)g * NN + n) * 2 + 0];
        ad1 = ald_all[((size_t)g * NN + n) * 2 + 1];
        float m0 = -1e30f, m1 = -1e30f;
        for (int i = lane; i < deg; i += 64) {
            int s = csr_src[start + i];
            float x0 = als[(size_t)s * 2 + 0] + ad0; x0 = x0 > 0.f ? x0 : NEG * x0;
            float x1 = als[(size_t)s * 2 + 1] + ad1; x1 = x1 > 0.f ? x1 : NEG * x1;
            m0 = fmaxf(m0, x0); m1 = fmaxf(m1, x1);
        }
#pragma unroll
        for (int off = 32; off; off >>= 1) {
            m0 = fmaxf(m0, __shfl_xor(m0, off));
            m1 = fmaxf(m1, __shfl_xor(m1, off));
        }
        float d0 = 0.f, d1 = 0.f;
        for (int i = lane; i < deg; i += 64) {
            int s = csr_src[start + i];
            float x0 = als[(size_t)s * 2 + 0] + ad0; x0 = x0 > 0.f ? x0 : NEG * x0;
            float x1 = als[(size_t)s * 2 + 1] + ad1; x1 = x1 > 0.f ? x1 : NEG * x1;
            d0 += __expf(x0 - m0); d1 += __expf(x1 - m1);
        }
#pragma unroll
        for (int off = 32; off; off >>= 1) {
            d0 += __shfl_xor(d0, off);
            d1 += __shfl_xor(d1, off);
        }
        if (lane == 0) { s_d[0] = d0; s_d[1] = d1; }
        mm0 = m0; mm1 = m1;
    }
    __syncthreads();

    const bf16* Hg = H + (size_t)g * NN * HIDD;
    float acc[8] = {0.f, 0.f, 0.f, 0.f, 0.f, 0.f, 0.f, 0.f};

    for (int c0 = 0; c0 < deg; c0 += CHUNK) {
        int cn = min(CHUNK, deg - c0);
        if (wave == 0) {
            for (int i = lane; i < cn; i += 64) {
                int s = csr_src[start + c0 + i];
                s_src[i] = s;
                float x0 = als[(size_t)s * 2 + 0] + ad0; x0 = x0 > 0.f ? x0 : NEG * x0;
                float x1 = als[(size_t)s * 2 + 1] + ad1; x1 = x1 > 0.f ? x1 : NEG * x1;
                s_w[0][i] = __expf(x0 - mm0);
                s_w[1][i] = __expf(x1 - mm1);
            }
        }
        __syncthreads();
        for (int i = grp; i < cn; i += 8) {
            int s = s_src[i];
            float wgt = s_w[hd_g][i];
            uint4 q = *(const uint4*)(Hg + (size_t)s * HIDD + lch * 8);
            acc[0] = fmaf(wgt, __uint_as_float(q.x << 16), acc[0]);
            acc[1] = fmaf(wgt, __uint_as_float(q.x & 0xffff0000u), acc[1]);
            acc[2] = fmaf(wgt, __uint_as_float(q.y << 16), acc[2]);
            acc[3] = fmaf(wgt, __uint_as_float(q.y & 0xffff0000u), acc[3]);
            acc[4] = fmaf(wgt, __uint_as_float(q.z << 16), acc[4]);
            acc[5] = fmaf(wgt, __uint_as_float(q.z & 0xffff0000u), acc[5]);
            acc[6] = fmaf(wgt, __uint_as_float(q.w << 16), acc[6]);
            acc[7] = fmaf(wgt, __uint_as_float(q.w & 0xffff0000u), acc[7]);
        }
        __syncthreads();
    }

    // reduce the 8 edge-groups
#pragma unroll
    for (int j = 0; j < 8; j++) s_acc[grp][lch * 8 + j] = acc[j];
    __syncthreads();

    float v = 0.f;
#pragma unroll
    for (int q = 0; q < 8; q++) v += s_acc[q][t];

    int hd = t >> 7;
    v = v / s_d[hd] + bias[t];

    // LayerNorm over 256 channels (block-wide)
    float s1 = v, s2 = v * v;
#pragma unroll
    for (int off = 32; off; off >>= 1) {
        s1 += __shfl_xor(s1, off);
        s2 += __shfl_xor(s2, off);
    }
    __shared__ float r1[4], r2[4];
    if (lane == 0) { r1[wave] = s1; r2[wave] = s2; }
    __syncthreads();
    float sum = r1[0] + r1[1] + r1[2] + r1[3];
    float sq  = r2[0] + r2[1] + r2[2] + r2[3];
    float mu  = sum * (1.f / HIDD);
    float var = sq * (1.f / HIDD) - mu * mu;
    float o = (v - mu) * rsqrtf(var + 1e-5f) * gam[t] + bet[t];
    o = fmaxf(o, 0.f);
    store_out(&out[(size_t)gn * HIDD + t], o);
}

// ---------------- launch ----------------
extern "C" void kernel_launch(void* const* d_in, const int* in_sizes, int n_in,
                              void* d_out, int out_size, void* d_ws, size_t ws_size,
                              hipStream_t stream) {
    const float* feature = (const float*)d_in[0];
    const int*   ei      = (const int*)d_in[1];
    const float* W1      = (const float*)d_in[2];
    const float* a_src1  = (const float*)d_in[3];
    const float* a_dst1  = (const float*)d_in[4];
    const float* b1      = (const float*)d_in[5];
    const float* g1      = (const float*)d_in[6];
    const float* be1     = (const float*)d_in[7];
    const float* W2      = (const float*)d_in[8];
    const float* a_src2  = (const float*)d_in[9];
    const float* a_dst2  = (const float*)d_in[10];
    const float* b2      = (const float*)d_in[11];
    const float* g2      = (const float*)d_in[12];
    const float* be2     = (const float*)d_in[13];
    float* out = (float*)d_out;

    const int E = in_sizes[1] / 2;
    const int* srcv = ei;
    const int* dstv = ei + E;

    char* w = (char*)d_ws;
    auto alloc = [&](size_t bytes) -> char* {
        char* p = w;
        w += (bytes + 255) & ~(size_t)255;
        return p;
    };
    int*   counts    = (int*)alloc(sizeof(int) * NN);
    int*   row_start = (int*)alloc(sizeof(int) * (NN + 1));
    int*   cursor    = (int*)alloc(sizeof(int) * NN);
    int*   csr_src   = (int*)alloc(sizeof(int) * E);
    float* als       = (float*)alloc(sizeof(float) * (size_t)BB * NN * 2);
    float* ald       = (float*)alloc(sizeof(float) * (size_t)BB * NN * 2);
    bf16*  featbf    = (bf16*)alloc(sizeof(bf16) * (size_t)BB * NN * DD);
    bf16*  h         = (bf16*)alloc(sizeof(bf16) * (size_t)BB * NN * HIDD);
    bf16*  x2        = (bf16*)alloc(sizeof(bf16) * (size_t)BB * NN * HIDD);
    bf16*  Wt        = (bf16*)alloc(sizeof(bf16) * HIDD * HIDD);

    // CSR build (shared by both layers, all graphs)
    zero_kernel<<<(NN + 255) / 256, 256, 0, stream>>>(counts, NN);
    hist_kernel<<<(E + 255) / 256, 256, 0, stream>>>(dstv, counts, E);
    scan_kernel<<<1, 1024, 0, stream>>>(counts, row_start, cursor);
    scatter_kernel<<<(E + 255) / 256, 256, 0, stream>>>(srcv, dstv, cursor, csr_src, E);

    // Layer 1
    {
        int nf = BB * NN * DD;
        convert_kernel<<<(nf + 255) / 256, 256, 0, stream>>>(feature, featbf, nf);
    }
    convwt_kernel<<<(DD * HIDD + 255) / 256, 256, 0, stream>>>(W1, Wt, DD);
    gemm_kernel<DD><<<dim3((NN + 63) / 64, BB), 256, 0, stream>>>(featbf, Wt, a_src1, a_dst1, h, als, ald);
    node_kernel<bf16><<<BB * NN, 256, 0, stream>>>(row_start, csr_src, als, ald, h, b1, g1, be1, x2);

    // Layer 2
    convwt_kernel<<<(HIDD * HIDD + 255) / 256, 256, 0, stream>>>(W2, Wt, HIDD);
    gemm_kernel<HIDD><<<dim3((NN + 63) / 64, BB), 256, 0, stream>>>(x2, Wt, a_src2, a_dst2, h, als, ald);
    node_kernel<float><<<BB * NN, 256, 0, stream>>>(row_start, csr_src, als, ald, h, b2, g2, be2, out);
}

// Round 4
// 390.651 us; speedup vs baseline: 1.2602x; 1.1374x over previous
//
#include <hip/hip_runtime.h>
#include <hip/hip_bf16.h>

#define NN   10000
#define BB   4
#define DD   128
#define HIDD 256
#define NEG  0.2f

using bf16 = __hip_bfloat16;
typedef __bf16 bf16x8 __attribute__((ext_vector_type(8)));
typedef float  f32x4  __attribute__((ext_vector_type(4)));

__device__ __forceinline__ float b2f(bf16 v) { return __bfloat162float(v); }
__device__ __forceinline__ void store_out(bf16* p, float v) { *p = __float2bfloat16(v); }
__device__ __forceinline__ void store_out(float* p, float v) { *p = v; }
__device__ __forceinline__ float lrelu(float x) { return x > 0.f ? x : NEG * x; }

// ---------------- fp32 -> bf16 conversions ----------------
__global__ void convert_kernel(const float* __restrict__ x, bf16* __restrict__ y, int n) {
    int i = blockIdx.x * 256 + threadIdx.x;
    if (i < n) y[i] = __float2bfloat16(x[i]);
}

// Wt[n][k] = bf16(W[k][n])
__global__ void convwt_kernel(const float* __restrict__ W, bf16* __restrict__ Wt, int K) {
    int idx = blockIdx.x * 256 + threadIdx.x;
    if (idx < K * HIDD) {
        int k = idx / HIDD, n = idx % HIDD;
        Wt[(size_t)n * K + k] = __float2bfloat16(W[idx]);
    }
}

// ---------------- CSR build ----------------
__global__ void zero_kernel(int* p, int n) {
    int i = blockIdx.x * 256 + threadIdx.x;
    if (i < n) p[i] = 0;
}

__global__ void hist_kernel(const int* __restrict__ dstv, int* counts, int E) {
    int e = blockIdx.x * 256 + threadIdx.x;
    if (e < E) atomicAdd(&counts[dstv[e]], 1);
}

__global__ __launch_bounds__(1024) void scan_kernel(const int* __restrict__ counts,
                                                    int* row_start, int* cursor) {
    __shared__ int part[1024];
    int t = threadIdx.x;
    const int CH = (NN + 1023) / 1024;  // 10
    int base = t * CH;
    int s = 0;
    for (int j = 0; j < CH; j++) { int idx = base + j; if (idx < NN) s += counts[idx]; }
    part[t] = s;
    __syncthreads();
    for (int off = 1; off < 1024; off <<= 1) {
        int v = (t >= off) ? part[t - off] : 0;
        __syncthreads();
        part[t] += v;
        __syncthreads();
    }
    int excl = (t == 0) ? 0 : part[t - 1];
    for (int j = 0; j < CH; j++) {
        int idx = base + j;
        if (idx < NN) { row_start[idx] = excl; cursor[idx] = excl; excl += counts[idx]; }
    }
    if (t == 1023) row_start[NN] = part[1023];
}

__global__ void scatter_kernel(const int* __restrict__ srcv, const int* __restrict__ dstv,
                               int* cursor, int* csr_src, int* csr_dst, int E) {
    int e = blockIdx.x * 256 + threadIdx.x;
    if (e < E) {
        int d = dstv[e];
        int p = atomicAdd(&cursor[d], 1);
        csr_src[p] = srcv[e];
        csr_dst[p] = d;
    }
}

// ---------------- GEMM + fused attention coefficients ----------------
// block: 64 rows x 128 cols (one head); wave: 16 rows x 128 cols via 8 MFMA.
template <int K>
__global__ __launch_bounds__(256) void gemm_kernel(const bf16* __restrict__ A,
                                                   const bf16* __restrict__ Wt,
                                                   const float* __restrict__ a_src,
                                                   const float* __restrict__ a_dst,
                                                   bf16* __restrict__ H,
                                                   float* __restrict__ als,
                                                   float* __restrict__ ald) {
    int g    = blockIdx.z;
    int head = blockIdx.y;
    int wave = threadIdx.x >> 6, lane = threadIdx.x & 63;
    int m0   = blockIdx.x * 64 + wave * 16;
    int lm   = lane & 15, lq = lane >> 4;

    int row = m0 + lm;
    if (row > NN - 1) row = NN - 1;  // clamp (stores guarded)
    const bf16* Arow = A + ((size_t)g * NN + row) * K + lq * 8;
    const bf16* Wh   = Wt + (size_t)head * 128 * K;

    f32x4 acc[8];
#pragma unroll
    for (int i = 0; i < 8; i++) acc[i] = (f32x4){0.f, 0.f, 0.f, 0.f};

#pragma unroll
    for (int k0 = 0; k0 < K; k0 += 32) {
        bf16x8 av = *(const bf16x8*)(Arow + k0);
#pragma unroll
        for (int fi = 0; fi < 8; fi++) {
            const bf16* Bp = Wh + (size_t)(fi * 16 + lm) * K + lq * 8 + k0;
            bf16x8 bv = *(const bf16x8*)Bp;
            acc[fi] = __builtin_amdgcn_mfma_f32_16x16x32_bf16(av, bv, acc[fi], 0, 0, 0);
        }
    }

    int crow0 = m0 + lq * 4;
    float ps[4] = {0.f, 0.f, 0.f, 0.f};
    float pd[4] = {0.f, 0.f, 0.f, 0.f};

#pragma unroll
    for (int fi = 0; fi < 8; fi++) {
        int col = head * 128 + fi * 16 + lm;
        float as = a_src[col], ad = a_dst[col];
#pragma unroll
        for (int r = 0; r < 4; r++) {
            float v = acc[fi][r];
            ps[r] = fmaf(v, as, ps[r]);
            pd[r] = fmaf(v, ad, pd[r]);
            int cr = crow0 + r;
            if (cr < NN)
                H[((size_t)g * NN + cr) * HIDD + col] = __float2bfloat16(v);
        }
    }

#pragma unroll
    for (int r = 0; r < 4; r++) {
        float a = ps[r], b = pd[r];
#pragma unroll
        for (int off = 1; off < 16; off <<= 1) {
            a += __shfl_xor(a, off);
            b += __shfl_xor(b, off);
        }
        if (lm == 0) {
            int cr = crow0 + r;
            if (cr < NN) {
                als[((size_t)g * NN + cr) * 2 + head] = a;
                ald[((size_t)g * NN + cr) * 2 + head] = b;
            }
        }
    }
}

// ---------------- per-node softmax stats: md[gn] = (m0, m1, 1/d0, 1/d1) ----------------
__global__ __launch_bounds__(256) void softmax_kernel(const int* __restrict__ row_start,
                                                      const int* __restrict__ csr_src,
                                                      const float* __restrict__ als,
                                                      const float* __restrict__ ald,
                                                      float4* __restrict__ md) {
    int wave = threadIdx.x >> 6, lane = threadIdx.x & 63;
    int gn = blockIdx.x * 4 + wave;
    if (gn >= BB * NN) return;
    int g = gn / NN, n = gn - g * NN;
    int start = row_start[n];
    int deg   = row_start[n + 1] - start;

    float2 ad = *(const float2*)&ald[(size_t)gn * 2];
    float m0 = -1e30f, m1 = -1e30f;
    for (int i = lane; i < deg; i += 64) {
        int s = csr_src[start + i];
        float2 as = *(const float2*)&als[((size_t)g * NN + s) * 2];
        m0 = fmaxf(m0, lrelu(as.x + ad.x));
        m1 = fmaxf(m1, lrelu(as.y + ad.y));
    }
#pragma unroll
    for (int off = 32; off; off >>= 1) {
        m0 = fmaxf(m0, __shfl_xor(m0, off));
        m1 = fmaxf(m1, __shfl_xor(m1, off));
    }
    float d0 = 0.f, d1 = 0.f;
    for (int i = lane; i < deg; i += 64) {
        int s = csr_src[start + i];
        float2 as = *(const float2*)&als[((size_t)g * NN + s) * 2];
        d0 += __expf(lrelu(as.x + ad.x) - m0);
        d1 += __expf(lrelu(as.y + ad.y) - m1);
    }
#pragma unroll
    for (int off = 32; off; off >>= 1) {
        d0 += __shfl_xor(d0, off);
        d1 += __shfl_xor(d1, off);
    }
    if (lane == 0)
        md[gn] = make_float4(m0, m1, 1.f / d0, 1.f / d1);
}

// ---------------- per-edge alpha (denominator folded in) ----------------
__global__ __launch_bounds__(256) void alpha_kernel(const int* __restrict__ csr_src,
                                                    const int* __restrict__ csr_dst,
                                                    const float* __restrict__ als,
                                                    const float* __restrict__ ald,
                                                    const float4* __restrict__ md,
                                                    float2* __restrict__ alpha, int E) {
    int idx = blockIdx.x * 256 + threadIdx.x;
    if (idx >= BB * E) return;
    int g = idx / E;
    int p = idx - g * E;
    int s = csr_src[p], d = csr_dst[p];
    float2 as = *(const float2*)&als[((size_t)g * NN + s) * 2];
    float2 av = *(const float2*)&ald[((size_t)g * NN + d) * 2];
    float4 m  = md[(size_t)g * NN + d];
    float a0 = __expf(lrelu(as.x + av.x) - m.x) * m.z;
    float a1 = __expf(lrelu(as.y + av.y) - m.y) * m.w;
    alpha[(size_t)g * E + p] = make_float2(a0, a1);
}

// ---------------- aggregate + bias + LN + ReLU, one block per (g,n) ----------------
// 8 edge-groups x 32 threads; each thread owns 8 contiguous channels (uint4 load)
template <typename OT>
__global__ __launch_bounds__(256) void node_kernel(const int* __restrict__ row_start,
                                                   const int* __restrict__ csr_src,
                                                   const float2* __restrict__ alpha,
                                                   const bf16* __restrict__ H,
                                                   const float* __restrict__ bias,
                                                   const float* __restrict__ gam,
                                                   const float* __restrict__ bet,
                                                   OT* __restrict__ out, int E) {
    int gn = blockIdx.x;
    int g  = gn / NN;
    int n  = gn - g * NN;
    int t = threadIdx.x, lane = t & 63, wave = t >> 6;
    int grp = t >> 5, lch = t & 31;
    int hd_g = lch >> 4;  // head of this thread's 8 channels
    int start = row_start[n];
    int deg   = row_start[n + 1] - start;

    __shared__ float s_acc[8][256];

    const bf16*  Hg = H + (size_t)g * NN * HIDD;
    const float* Al = (const float*)(alpha + (size_t)g * E + start);
    const int*   Sr = csr_src + start;

    float acc[8] = {0.f, 0.f, 0.f, 0.f, 0.f, 0.f, 0.f, 0.f};

    int i = grp;
    while (i + 8 < deg) {
        int s0 = Sr[i], s1 = Sr[i + 8];
        float w0 = Al[i * 2 + hd_g], w1 = Al[(i + 8) * 2 + hd_g];
        uint4 q0 = *(const uint4*)(Hg + (size_t)s0 * HIDD + lch * 8);
        uint4 q1 = *(const uint4*)(Hg + (size_t)s1 * HIDD + lch * 8);
        acc[0] = fmaf(w0, __uint_as_float(q0.x << 16), acc[0]);
        acc[1] = fmaf(w0, __uint_as_float(q0.x & 0xffff0000u), acc[1]);
        acc[2] = fmaf(w0, __uint_as_float(q0.y << 16), acc[2]);
        acc[3] = fmaf(w0, __uint_as_float(q0.y & 0xffff0000u), acc[3]);
        acc[4] = fmaf(w0, __uint_as_float(q0.z << 16), acc[4]);
        acc[5] = fmaf(w0, __uint_as_float(q0.z & 0xffff0000u), acc[5]);
        acc[6] = fmaf(w0, __uint_as_float(q0.w << 16), acc[6]);
        acc[7] = fmaf(w0, __uint_as_float(q0.w & 0xffff0000u), acc[7]);
        acc[0] = fmaf(w1, __uint_as_float(q1.x << 16), acc[0]);
        acc[1] = fmaf(w1, __uint_as_float(q1.x & 0xffff0000u), acc[1]);
        acc[2] = fmaf(w1, __uint_as_float(q1.y << 16), acc[2]);
        acc[3] = fmaf(w1, __uint_as_float(q1.y & 0xffff0000u), acc[3]);
        acc[4] = fmaf(w1, __uint_as_float(q1.z << 16), acc[4]);
        acc[5] = fmaf(w1, __uint_as_float(q1.z & 0xffff0000u), acc[5]);
        acc[6] = fmaf(w1, __uint_as_float(q1.w << 16), acc[6]);
        acc[7] = fmaf(w1, __uint_as_float(q1.w & 0xffff0000u), acc[7]);
        i += 16;
    }
    if (i < deg) {
        int s0 = Sr[i];
        float w0 = Al[i * 2 + hd_g];
        uint4 q0 = *(const uint4*)(Hg + (size_t)s0 * HIDD + lch * 8);
        acc[0] = fmaf(w0, __uint_as_float(q0.x << 16), acc[0]);
        acc[1] = fmaf(w0, __uint_as_float(q0.x & 0xffff0000u), acc[1]);
        acc[2] = fmaf(w0, __uint_as_float(q0.y << 16), acc[2]);
        acc[3] = fmaf(w0, __uint_as_float(q0.y & 0xffff0000u), acc[3]);
        acc[4] = fmaf(w0, __uint_as_float(q0.z << 16), acc[4]);
        acc[5] = fmaf(w0, __uint_as_float(q0.z & 0xffff0000u), acc[5]);
        acc[6] = fmaf(w0, __uint_as_float(q0.w << 16), acc[6]);
        acc[7] = fmaf(w0, __uint_as_float(q0.w & 0xffff0000u), acc[7]);
    }

    // swizzled conflict-free reduce of the 8 edge-groups
    int sw = lch >> 2;
#pragma unroll
    for (int j = 0; j < 8; j++)
        s_acc[grp][lch * 8 + ((j + sw) & 7)] = acc[j];
    __syncthreads();

    int rcol = (t & ~7) | (((t & 7) + (t >> 5)) & 7);
    float v = 0.f;
#pragma unroll
    for (int q = 0; q < 8; q++) v += s_acc[q][rcol];

    v += bias[t];

    // LayerNorm over 256 channels (block-wide)
    float s1 = v, s2 = v * v;
#pragma unroll
    for (int off = 32; off; off >>= 1) {
        s1 += __shfl_xor(s1, off);
        s2 += __shfl_xor(s2, off);
    }
    __shared__ float r1[4], r2[4];
    if (lane == 0) { r1[wave] = s1; r2[wave] = s2; }
    __syncthreads();
    float sum = r1[0] + r1[1] + r1[2] + r1[3];
    float sq  = r2[0] + r2[1] + r2[2] + r2[3];
    float mu  = sum * (1.f / HIDD);
    float var = sq * (1.f / HIDD) - mu * mu;
    float o = (v - mu) * rsqrtf(var + 1e-5f) * gam[t] + bet[t];
    o = fmaxf(o, 0.f);
    store_out(&out[(size_t)gn * HIDD + t], o);
}

// ---------------- launch ----------------
extern "C" void kernel_launch(void* const* d_in, const int* in_sizes, int n_in,
                              void* d_out, int out_size, void* d_ws, size_t ws_size,
                              hipStream_t stream) {
    const float* feature = (const float*)d_in[0];
    const int*   ei      = (const int*)d_in[1];
    const float* W1      = (const float*)d_in[2];
    const float* a_src1  = (const float*)d_in[3];
    const float* a_dst1  = (const float*)d_in[4];
    const float* b1      = (const float*)d_in[5];
    const float* g1      = (const float*)d_in[6];
    const float* be1     = (const float*)d_in[7];
    const float* W2      = (const float*)d_in[8];
    const float* a_src2  = (const float*)d_in[9];
    const float* a_dst2  = (const float*)d_in[10];
    const float* b2      = (const float*)d_in[11];
    const float* g2      = (const float*)d_in[12];
    const float* be2     = (const float*)d_in[13];
    float* out = (float*)d_out;

    const int E = in_sizes[1] / 2;
    const int* srcv = ei;
    const int* dstv = ei + E;

    char* w = (char*)d_ws;
    auto alloc = [&](size_t bytes) -> char* {
        char* p = w;
        w += (bytes + 255) & ~(size_t)255;
        return p;
    };
    int*    counts    = (int*)alloc(sizeof(int) * NN);
    int*    row_start = (int*)alloc(sizeof(int) * (NN + 1));
    int*    cursor    = (int*)alloc(sizeof(int) * NN);
    int*    csr_src   = (int*)alloc(sizeof(int) * E);
    int*    csr_dst   = (int*)alloc(sizeof(int) * E);
    float*  als       = (float*)alloc(sizeof(float) * (size_t)BB * NN * 2);
    float*  ald       = (float*)alloc(sizeof(float) * (size_t)BB * NN * 2);
    float4* md        = (float4*)alloc(sizeof(float4) * (size_t)BB * NN);
    float2* alphab    = (float2*)alloc(sizeof(float2) * (size_t)BB * E);
    bf16*   featbf    = (bf16*)alloc(sizeof(bf16) * (size_t)BB * NN * DD);
    bf16*   h         = (bf16*)alloc(sizeof(bf16) * (size_t)BB * NN * HIDD);
    bf16*   x2        = (bf16*)alloc(sizeof(bf16) * (size_t)BB * NN * HIDD);
    bf16*   Wt        = (bf16*)alloc(sizeof(bf16) * HIDD * HIDD);

    // CSR build (shared by both layers, all graphs)
    zero_kernel<<<(NN + 255) / 256, 256, 0, stream>>>(counts, NN);
    hist_kernel<<<(E + 255) / 256, 256, 0, stream>>>(dstv, counts, E);
    scan_kernel<<<1, 1024, 0, stream>>>(counts, row_start, cursor);
    scatter_kernel<<<(E + 255) / 256, 256, 0, stream>>>(srcv, dstv, cursor, csr_src, csr_dst, E);

    // Layer 1
    {
        int nf = BB * NN * DD;
        convert_kernel<<<(nf + 255) / 256, 256, 0, stream>>>(feature, featbf, nf);
    }
    convwt_kernel<<<(DD * HIDD + 255) / 256, 256, 0, stream>>>(W1, Wt, DD);
    gemm_kernel<DD><<<dim3((NN + 63) / 64, 2, BB), 256, 0, stream>>>(featbf, Wt, a_src1, a_dst1, h, als, ald);
    softmax_kernel<<<(BB * NN + 3) / 4, 256, 0, stream>>>(row_start, csr_src, als, ald, md);
    alpha_kernel<<<(BB * E + 255) / 256, 256, 0, stream>>>(csr_src, csr_dst, als, ald, md, alphab, E);
    node_kernel<bf16><<<BB * NN, 256, 0, stream>>>(row_start, csr_src, alphab, h, b1, g1, be1, x2, E);

    // Layer 2
    convwt_kernel<<<(HIDD * HIDD + 255) / 256, 256, 0, stream>>>(W2, Wt, HIDD);
    gemm_kernel<HIDD><<<dim3((NN + 63) / 64, 2, BB), 256, 0, stream>>>(x2, Wt, a_src2, a_dst2, h, als, ald);
    softmax_kernel<<<(BB * NN + 3) / 4, 256, 0, stream>>>(row_start, csr_src, als, ald, md);
    alpha_kernel<<<(BB * E + 255) / 256, 256, 0, stream>>>(csr_src, csr_dst, als, ald, md, alphab, E);
    node_kernel<float><<<BB * NN, 256, 0, stream>>>(row_start, csr_src, alphab, h, b2, g2, be2, out, E);
}

// Round 5
// 368.580 us; speedup vs baseline: 1.3356x; 1.0599x over previous
//
#include <hip/hip_runtime.h>
#include <hip/hip_bf16.h>

#define NN   10000
#define BB   4
#define DD   128
#define HIDD 256
#define NEG  0.2f

using bf16 = __hip_bfloat16;
typedef __bf16 bf16x8 __attribute__((ext_vector_type(8)));
typedef float  f32x4  __attribute__((ext_vector_type(4)));

__device__ __forceinline__ float b2f(bf16 v) { return __bfloat162float(v); }
__device__ __forceinline__ void store_out(bf16* p, float v) { *p = __float2bfloat16(v); }
__device__ __forceinline__ void store_out(float* p, float v) { *p = v; }
__device__ __forceinline__ float lrelu(float x) { return x > 0.f ? x : NEG * x; }

// ---------------- fp32 -> bf16 conversions ----------------
__global__ void convert_kernel(const float* __restrict__ x, bf16* __restrict__ y, int n) {
    int i = blockIdx.x * 256 + threadIdx.x;
    if (i < n) y[i] = __float2bfloat16(x[i]);
}

// Wt[n][k] = bf16(W[k][n])
__global__ void convwt_kernel(const float* __restrict__ W, bf16* __restrict__ Wt, int K) {
    int idx = blockIdx.x * 256 + threadIdx.x;
    if (idx < K * HIDD) {
        int k = idx / HIDD, n = idx % HIDD;
        Wt[(size_t)n * K + k] = __float2bfloat16(W[idx]);
    }
}

// ---------------- CSR build ----------------
__global__ void zero_kernel(int* p, int n) {
    int i = blockIdx.x * 256 + threadIdx.x;
    if (i < n) p[i] = 0;
}

__global__ void hist_kernel(const int* __restrict__ dstv, int* counts, int E) {
    int e = blockIdx.x * 256 + threadIdx.x;
    if (e < E) atomicAdd(&counts[dstv[e]], 1);
}

__global__ __launch_bounds__(1024) void scan_kernel(const int* __restrict__ counts,
                                                    int* row_start, int* cursor) {
    __shared__ int part[1024];
    int t = threadIdx.x;
    const int CH = (NN + 1023) / 1024;  // 10
    int base = t * CH;
    int s = 0;
    for (int j = 0; j < CH; j++) { int idx = base + j; if (idx < NN) s += counts[idx]; }
    part[t] = s;
    __syncthreads();
    for (int off = 1; off < 1024; off <<= 1) {
        int v = (t >= off) ? part[t - off] : 0;
        __syncthreads();
        part[t] += v;
        __syncthreads();
    }
    int excl = (t == 0) ? 0 : part[t - 1];
    for (int j = 0; j < CH; j++) {
        int idx = base + j;
        if (idx < NN) { row_start[idx] = excl; cursor[idx] = excl; excl += counts[idx]; }
    }
    if (t == 1023) row_start[NN] = part[1023];
}

__global__ void scatter_kernel(const int* __restrict__ srcv, const int* __restrict__ dstv,
                               int* cursor, int* csr_src, int* csr_dst, int E) {
    int e = blockIdx.x * 256 + threadIdx.x;
    if (e < E) {
        int d = dstv[e];
        int p = atomicAdd(&cursor[d], 1);
        csr_src[p] = srcv[e];
        csr_dst[p] = d;
    }
}

// ---------------- GEMM + fused attention coefficients ----------------
// block: 128 rows x 128 cols (one head); wave: 32 rows x 128 cols via 16 MFMA
// (8 B-fragments reused across 2 row-subtiles).
template <int K>
__global__ __launch_bounds__(256) void gemm_kernel(const bf16* __restrict__ A,
                                                   const bf16* __restrict__ Wt,
                                                   const float* __restrict__ a_src,
                                                   const float* __restrict__ a_dst,
                                                   bf16* __restrict__ H,
                                                   float* __restrict__ als,
                                                   float* __restrict__ ald) {
    int g    = blockIdx.z;
    int head = blockIdx.y;
    int wave = threadIdx.x >> 6, lane = threadIdx.x & 63;
    int m0   = blockIdx.x * 128 + wave * 32;
    int lm   = lane & 15, lq = lane >> 4;

    int rowA = m0 + lm;      if (rowA > NN - 1) rowA = NN - 1;
    int rowB = m0 + 16 + lm; if (rowB > NN - 1) rowB = NN - 1;
    const bf16* Ar0 = A + ((size_t)g * NN + rowA) * K + lq * 8;
    const bf16* Ar1 = A + ((size_t)g * NN + rowB) * K + lq * 8;
    const bf16* Wh  = Wt + (size_t)head * 128 * K;

    f32x4 acc[2][8];
#pragma unroll
    for (int rb = 0; rb < 2; rb++)
#pragma unroll
        for (int i = 0; i < 8; i++) acc[rb][i] = (f32x4){0.f, 0.f, 0.f, 0.f};

#pragma unroll
    for (int k0 = 0; k0 < K; k0 += 32) {
        bf16x8 a0 = *(const bf16x8*)(Ar0 + k0);
        bf16x8 a1 = *(const bf16x8*)(Ar1 + k0);
#pragma unroll
        for (int fi = 0; fi < 8; fi++) {
            const bf16* Bp = Wh + (size_t)(fi * 16 + lm) * K + lq * 8 + k0;
            bf16x8 bv = *(const bf16x8*)Bp;
            acc[0][fi] = __builtin_amdgcn_mfma_f32_16x16x32_bf16(a0, bv, acc[0][fi], 0, 0, 0);
            acc[1][fi] = __builtin_amdgcn_mfma_f32_16x16x32_bf16(a1, bv, acc[1][fi], 0, 0, 0);
        }
    }

#pragma unroll
    for (int rb = 0; rb < 2; rb++) {
        int crow0 = m0 + rb * 16 + lq * 4;
        float ps[4] = {0.f, 0.f, 0.f, 0.f};
        float pd[4] = {0.f, 0.f, 0.f, 0.f};
#pragma unroll
        for (int fi = 0; fi < 8; fi++) {
            int col = head * 128 + fi * 16 + lm;
            float as = a_src[col], ad = a_dst[col];
#pragma unroll
            for (int r = 0; r < 4; r++) {
                float v = acc[rb][fi][r];
                ps[r] = fmaf(v, as, ps[r]);
                pd[r] = fmaf(v, ad, pd[r]);
                int cr = crow0 + r;
                if (cr < NN)
                    H[((size_t)g * NN + cr) * HIDD + col] = __float2bfloat16(v);
            }
        }
#pragma unroll
        for (int r = 0; r < 4; r++) {
            float a = ps[r], b = pd[r];
#pragma unroll
            for (int off = 1; off < 16; off <<= 1) {
                a += __shfl_xor(a, off);
                b += __shfl_xor(b, off);
            }
            if (lm == 0) {
                int cr = crow0 + r;
                if (cr < NN) {
                    als[((size_t)g * NN + cr) * 2 + head] = a;
                    ald[((size_t)g * NN + cr) * 2 + head] = b;
                }
            }
        }
    }
}

// ---------------- per-edge leaky-relu logits (gathered once, then linear) ----------------
__global__ __launch_bounds__(256) void logit_kernel(const int* __restrict__ csr_src,
                                                    const int* __restrict__ csr_dst,
                                                    const float2* __restrict__ als2,
                                                    const float2* __restrict__ ald2,
                                                    float2* __restrict__ elog, int E) {
    int idx = blockIdx.x * 256 + threadIdx.x;
    if (idx >= BB * E) return;
    int g = idx / E;
    int p = idx - g * E;
    int s = csr_src[p], d = csr_dst[p];
    float2 as = als2[(size_t)g * NN + s];
    float2 ad = ald2[(size_t)g * NN + d];
    elog[(size_t)g * E + p] = make_float2(lrelu(as.x + ad.x), lrelu(as.y + ad.y));
}

// ---------------- per-node softmax stats (linear reads): md = (m0,m1,1/d0,1/d1) ----------------
__global__ __launch_bounds__(256) void softmax_kernel(const int* __restrict__ row_start,
                                                      const float2* __restrict__ elog,
                                                      float4* __restrict__ md, int E) {
    int wave = threadIdx.x >> 6, lane = threadIdx.x & 63;
    int gn = blockIdx.x * 4 + wave;
    if (gn >= BB * NN) return;
    int g = gn / NN, n = gn - g * NN;
    int start = row_start[n];
    int deg   = row_start[n + 1] - start;
    const float2* e = elog + (size_t)g * E + start;

    float m0 = -1e30f, m1 = -1e30f;
    for (int i = lane; i < deg; i += 64) {
        float2 v = e[i];
        m0 = fmaxf(m0, v.x); m1 = fmaxf(m1, v.y);
    }
#pragma unroll
    for (int off = 32; off; off >>= 1) {
        m0 = fmaxf(m0, __shfl_xor(m0, off));
        m1 = fmaxf(m1, __shfl_xor(m1, off));
    }
    float d0 = 0.f, d1 = 0.f;
    for (int i = lane; i < deg; i += 64) {
        float2 v = e[i];
        d0 += __expf(v.x - m0); d1 += __expf(v.y - m1);
    }
#pragma unroll
    for (int off = 32; off; off >>= 1) {
        d0 += __shfl_xor(d0, off);
        d1 += __shfl_xor(d1, off);
    }
    if (lane == 0)
        md[gn] = make_float4(m0, m1, 1.f / d0, 1.f / d1);
}

// ---------------- per-edge record: {src_bits, alpha0, alpha1, pad} ----------------
__global__ __launch_bounds__(256) void alpha_kernel(const int* __restrict__ csr_src,
                                                    const int* __restrict__ csr_dst,
                                                    const float2* __restrict__ elog,
                                                    const float4* __restrict__ md,
                                                    float4* __restrict__ rec, int E) {
    int idx = blockIdx.x * 256 + threadIdx.x;
    if (idx >= BB * E) return;
    int g = idx / E;
    int p = idx - g * E;
    int d = csr_dst[p];
    float2 el = elog[(size_t)g * E + p];
    float4 m  = md[(size_t)g * NN + d];
    float a0 = __expf(el.x - m.x) * m.z;
    float a1 = __expf(el.y - m.y) * m.w;
    rec[(size_t)g * E + p] = make_float4(__int_as_float(csr_src[p]), a0, a1, 0.f);
}

// ---------------- aggregate + bias + LN + ReLU, one block per (g,n) ----------------
// 8 edge-groups x 32 threads; each thread owns 8 contiguous channels (uint4 load);
// one float4 record load per edge.
template <typename OT>
__global__ __launch_bounds__(256) void node_kernel(const int* __restrict__ row_start,
                                                   const float4* __restrict__ rec,
                                                   const bf16* __restrict__ H,
                                                   const float* __restrict__ bias,
                                                   const float* __restrict__ gam,
                                                   const float* __restrict__ bet,
                                                   OT* __restrict__ out, int E) {
    int gn = blockIdx.x;
    int g  = gn / NN;
    int n  = gn - g * NN;
    int t = threadIdx.x, lane = t & 63, wave = t >> 6;
    int grp = t >> 5, lch = t & 31;
    int hd_g = lch >> 4;  // head of this thread's 8 channels
    int start = row_start[n];
    int deg   = row_start[n + 1] - start;

    __shared__ float s_acc[8][256];

    const bf16*   Hg = H + (size_t)g * NN * HIDD;
    const float4* R  = rec + (size_t)g * E + start;

    float acc[8] = {0.f, 0.f, 0.f, 0.f, 0.f, 0.f, 0.f, 0.f};

    int i = grp;
    for (; i + 8 < deg; i += 16) {
        float4 r0 = R[i], r1 = R[i + 8];
        int s0 = __float_as_int(r0.x), s1 = __float_as_int(r1.x);
        float w0 = hd_g ? r0.z : r0.y;
        float w1 = hd_g ? r1.z : r1.y;
        uint4 q0 = *(const uint4*)(Hg + (size_t)s0 * HIDD + lch * 8);
        uint4 q1 = *(const uint4*)(Hg + (size_t)s1 * HIDD + lch * 8);
        acc[0] = fmaf(w0, __uint_as_float(q0.x << 16), acc[0]);
        acc[1] = fmaf(w0, __uint_as_float(q0.x & 0xffff0000u), acc[1]);
        acc[2] = fmaf(w0, __uint_as_float(q0.y << 16), acc[2]);
        acc[3] = fmaf(w0, __uint_as_float(q0.y & 0xffff0000u), acc[3]);
        acc[4] = fmaf(w0, __uint_as_float(q0.z << 16), acc[4]);
        acc[5] = fmaf(w0, __uint_as_float(q0.z & 0xffff0000u), acc[5]);
        acc[6] = fmaf(w0, __uint_as_float(q0.w << 16), acc[6]);
        acc[7] = fmaf(w0, __uint_as_float(q0.w & 0xffff0000u), acc[7]);
        acc[0] = fmaf(w1, __uint_as_float(q1.x << 16), acc[0]);
        acc[1] = fmaf(w1, __uint_as_float(q1.x & 0xffff0000u), acc[1]);
        acc[2] = fmaf(w1, __uint_as_float(q1.y << 16), acc[2]);
        acc[3] = fmaf(w1, __uint_as_float(q1.y & 0xffff0000u), acc[3]);
        acc[4] = fmaf(w1, __uint_as_float(q1.z << 16), acc[4]);
        acc[5] = fmaf(w1, __uint_as_float(q1.z & 0xffff0000u), acc[5]);
        acc[6] = fmaf(w1, __uint_as_float(q1.w << 16), acc[6]);
        acc[7] = fmaf(w1, __uint_as_float(q1.w & 0xffff0000u), acc[7]);
    }
    if (i < deg) {
        float4 r0 = R[i];
        int s0 = __float_as_int(r0.x);
        float w0 = hd_g ? r0.z : r0.y;
        uint4 q0 = *(const uint4*)(Hg + (size_t)s0 * HIDD + lch * 8);
        acc[0] = fmaf(w0, __uint_as_float(q0.x << 16), acc[0]);
        acc[1] = fmaf(w0, __uint_as_float(q0.x & 0xffff0000u), acc[1]);
        acc[2] = fmaf(w0, __uint_as_float(q0.y << 16), acc[2]);
        acc[3] = fmaf(w0, __uint_as_float(q0.y & 0xffff0000u), acc[3]);
        acc[4] = fmaf(w0, __uint_as_float(q0.z << 16), acc[4]);
        acc[5] = fmaf(w0, __uint_as_float(q0.z & 0xffff0000u), acc[5]);
        acc[6] = fmaf(w0, __uint_as_float(q0.w << 16), acc[6]);
        acc[7] = fmaf(w0, __uint_as_float(q0.w & 0xffff0000u), acc[7]);
    }

    // swizzled conflict-free reduce of the 8 edge-groups
    int sw = lch >> 2;
#pragma unroll
    for (int j = 0; j < 8; j++)
        s_acc[grp][lch * 8 + ((j + sw) & 7)] = acc[j];
    __syncthreads();

    int rcol = (t & ~7) | (((t & 7) + (t >> 5)) & 7);
    float v = 0.f;
#pragma unroll
    for (int q = 0; q < 8; q++) v += s_acc[q][rcol];

    v += bias[t];

    // LayerNorm over 256 channels (block-wide)
    float s1 = v, s2 = v * v;
#pragma unroll
    for (int off = 32; off; off >>= 1) {
        s1 += __shfl_xor(s1, off);
        s2 += __shfl_xor(s2, off);
    }
    __shared__ float r1[4], r2[4];
    if (lane == 0) { r1[wave] = s1; r2[wave] = s2; }
    __syncthreads();
    float sum = r1[0] + r1[1] + r1[2] + r1[3];
    float sq  = r2[0] + r2[1] + r2[2] + r2[3];
    float mu  = sum * (1.f / HIDD);
    float var = sq * (1.f / HIDD) - mu * mu;
    float o = (v - mu) * rsqrtf(var + 1e-5f) * gam[t] + bet[t];
    o = fmaxf(o, 0.f);
    store_out(&out[(size_t)gn * HIDD + t], o);
}

// ---------------- launch ----------------
extern "C" void kernel_launch(void* const* d_in, const int* in_sizes, int n_in,
                              void* d_out, int out_size, void* d_ws, size_t ws_size,
                              hipStream_t stream) {
    const float* feature = (const float*)d_in[0];
    const int*   ei      = (const int*)d_in[1];
    const float* W1      = (const float*)d_in[2];
    const float* a_src1  = (const float*)d_in[3];
    const float* a_dst1  = (const float*)d_in[4];
    const float* b1      = (const float*)d_in[5];
    const float* g1      = (const float*)d_in[6];
    const float* be1     = (const float*)d_in[7];
    const float* W2      = (const float*)d_in[8];
    const float* a_src2  = (const float*)d_in[9];
    const float* a_dst2  = (const float*)d_in[10];
    const float* b2      = (const float*)d_in[11];
    const float* g2      = (const float*)d_in[12];
    const float* be2     = (const float*)d_in[13];
    float* out = (float*)d_out;

    const int E = in_sizes[1] / 2;
    const int* srcv = ei;
    const int* dstv = ei + E;

    char* w = (char*)d_ws;
    auto alloc = [&](size_t bytes) -> char* {
        char* p = w;
        w += (bytes + 255) & ~(size_t)255;
        return p;
    };
    int*    counts    = (int*)alloc(sizeof(int) * NN);
    int*    row_start = (int*)alloc(sizeof(int) * (NN + 1));
    int*    cursor    = (int*)alloc(sizeof(int) * NN);
    int*    csr_src   = (int*)alloc(sizeof(int) * E);
    int*    csr_dst   = (int*)alloc(sizeof(int) * E);
    float*  als       = (float*)alloc(sizeof(float) * (size_t)BB * NN * 2);
    float*  ald       = (float*)alloc(sizeof(float) * (size_t)BB * NN * 2);
    float4* md        = (float4*)alloc(sizeof(float4) * (size_t)BB * NN);
    float2* elog      = (float2*)alloc(sizeof(float2) * (size_t)BB * E);
    float4* rec       = (float4*)alloc(sizeof(float4) * (size_t)BB * E);
    bf16*   featbf    = (bf16*)alloc(sizeof(bf16) * (size_t)BB * NN * DD);
    bf16*   h         = (bf16*)alloc(sizeof(bf16) * (size_t)BB * NN * HIDD);
    bf16*   x2        = (bf16*)alloc(sizeof(bf16) * (size_t)BB * NN * HIDD);
    bf16*   Wt        = (bf16*)alloc(sizeof(bf16) * HIDD * HIDD);

    // CSR build (shared by both layers, all graphs)
    zero_kernel<<<(NN + 255) / 256, 256, 0, stream>>>(counts, NN);
    hist_kernel<<<(E + 255) / 256, 256, 0, stream>>>(dstv, counts, E);
    scan_kernel<<<1, 1024, 0, stream>>>(counts, row_start, cursor);
    scatter_kernel<<<(E + 255) / 256, 256, 0, stream>>>(srcv, dstv, cursor, csr_src, csr_dst, E);

    int eblk = (BB * E + 255) / 256;

    // Layer 1
    {
        int nf = BB * NN * DD;
        convert_kernel<<<(nf + 255) / 256, 256, 0, stream>>>(feature, featbf, nf);
    }
    convwt_kernel<<<(DD * HIDD + 255) / 256, 256, 0, stream>>>(W1, Wt, DD);
    gemm_kernel<DD><<<dim3((NN + 127) / 128, 2, BB), 256, 0, stream>>>(featbf, Wt, a_src1, a_dst1, h, als, ald);
    logit_kernel<<<eblk, 256, 0, stream>>>(csr_src, csr_dst, (const float2*)als, (const float2*)ald, elog, E);
    softmax_kernel<<<(BB * NN + 3) / 4, 256, 0, stream>>>(row_start, elog, md, E);
    alpha_kernel<<<eblk, 256, 0, stream>>>(csr_src, csr_dst, elog, md, rec, E);
    node_kernel<bf16><<<BB * NN, 256, 0, stream>>>(row_start, rec, h, b1, g1, be1, x2, E);

    // Layer 2
    convwt_kernel<<<(HIDD * HIDD + 255) / 256, 256, 0, stream>>>(W2, Wt, HIDD);
    gemm_kernel<HIDD><<<dim3((NN + 127) / 128, 2, BB), 256, 0, stream>>>(x2, Wt, a_src2, a_dst2, h, als, ald);
    logit_kernel<<<eblk, 256, 0, stream>>>(csr_src, csr_dst, (const float2*)als, (const float2*)ald, elog, E);
    softmax_kernel<<<(BB * NN + 3) / 4, 256, 0, stream>>>(row_start, elog, md, E);
    alpha_kernel<<<eblk, 256, 0, stream>>>(csr_src, csr_dst, elog, md, rec, E);
    node_kernel<float><<<BB * NN, 256, 0, stream>>>(row_start, rec, h, b2, g2, be2, out, E);
}

// Round 6
// 313.245 us; speedup vs baseline: 1.5716x; 1.1766x over previous
//
#include <hip/hip_runtime.h>
#include <hip/hip_bf16.h>

#define NN   10000
#define BB   4
#define DD   128
#define HIDD 256
#define NEG  0.2f

using bf16 = __hip_bfloat16;
typedef __bf16 bf16x8 __attribute__((ext_vector_type(8)));
typedef float  f32x4  __attribute__((ext_vector_type(4)));

__device__ __forceinline__ float b2f(bf16 v) { return __bfloat162float(v); }
__device__ __forceinline__ float lrelu(float x) { return x > 0.f ? x : NEG * x; }

__device__ __forceinline__ unsigned pack2(float a, float b) {
    unsigned lo = __bfloat16_as_ushort(__float2bfloat16(a));
    unsigned hi = __bfloat16_as_ushort(__float2bfloat16(b));
    return lo | (hi << 16);
}

// ---------------- fp32 -> bf16 conversions ----------------
__global__ void convert_kernel(const float* __restrict__ x, bf16* __restrict__ y, int n) {
    int i = blockIdx.x * 256 + threadIdx.x;
    if (i < n) y[i] = __float2bfloat16(x[i]);
}

// Wt[n][k] = bf16(W[k][n])
__global__ void convwt_kernel(const float* __restrict__ W, bf16* __restrict__ Wt, int K) {
    int idx = blockIdx.x * 256 + threadIdx.x;
    if (idx < K * HIDD) {
        int k = idx / HIDD, n = idx % HIDD;
        Wt[(size_t)n * K + k] = __float2bfloat16(W[idx]);
    }
}

// ---------------- CSR build ----------------
__global__ void zero_kernel(int* p, int n) {
    int i = blockIdx.x * 256 + threadIdx.x;
    if (i < n) p[i] = 0;
}

__global__ void hist_kernel(const int* __restrict__ dstv, int* counts, int E) {
    int e = blockIdx.x * 256 + threadIdx.x;
    if (e < E) atomicAdd(&counts[dstv[e]], 1);
}

__global__ __launch_bounds__(1024) void scan_kernel(const int* __restrict__ counts,
                                                    int* row_start, int* cursor) {
    __shared__ int part[1024];
    int t = threadIdx.x;
    const int CH = (NN + 1023) / 1024;  // 10
    int base = t * CH;
    int s = 0;
    for (int j = 0; j < CH; j++) { int idx = base + j; if (idx < NN) s += counts[idx]; }
    part[t] = s;
    __syncthreads();
    for (int off = 1; off < 1024; off <<= 1) {
        int v = (t >= off) ? part[t - off] : 0;
        __syncthreads();
        part[t] += v;
        __syncthreads();
    }
    int excl = (t == 0) ? 0 : part[t - 1];
    for (int j = 0; j < CH; j++) {
        int idx = base + j;
        if (idx < NN) { row_start[idx] = excl; cursor[idx] = excl; excl += counts[idx]; }
    }
    if (t == 1023) row_start[NN] = part[1023];
}

__global__ void scatter_kernel(const int* __restrict__ srcv, const int* __restrict__ dstv,
                               int* cursor, int* csr_src, int E) {
    int e = blockIdx.x * 256 + threadIdx.x;
    if (e < E) {
        int d = dstv[e];
        int p = atomicAdd(&cursor[d], 1);
        csr_src[p] = srcv[e];
    }
}

// ---------------- GEMM + fused attention coefficients ----------------
// block: 128 rows x 128 cols (one head); wave: 32 rows x 128 cols via 16 MFMA
template <int K>
__global__ __launch_bounds__(256) void gemm_kernel(const bf16* __restrict__ A,
                                                   const bf16* __restrict__ Wt,
                                                   const float* __restrict__ a_src,
                                                   const float* __restrict__ a_dst,
                                                   bf16* __restrict__ H,
                                                   float* __restrict__ als,
                                                   float* __restrict__ ald) {
    int g    = blockIdx.z;
    int head = blockIdx.y;
    int wave = threadIdx.x >> 6, lane = threadIdx.x & 63;
    int m0   = blockIdx.x * 128 + wave * 32;
    int lm   = lane & 15, lq = lane >> 4;

    int rowA = m0 + lm;      if (rowA > NN - 1) rowA = NN - 1;
    int rowB = m0 + 16 + lm; if (rowB > NN - 1) rowB = NN - 1;
    const bf16* Ar0 = A + ((size_t)g * NN + rowA) * K + lq * 8;
    const bf16* Ar1 = A + ((size_t)g * NN + rowB) * K + lq * 8;
    const bf16* Wh  = Wt + (size_t)head * 128 * K;

    f32x4 acc[2][8];
#pragma unroll
    for (int rb = 0; rb < 2; rb++)
#pragma unroll
        for (int i = 0; i < 8; i++) acc[rb][i] = (f32x4){0.f, 0.f, 0.f, 0.f};

#pragma unroll
    for (int k0 = 0; k0 < K; k0 += 32) {
        bf16x8 a0 = *(const bf16x8*)(Ar0 + k0);
        bf16x8 a1 = *(const bf16x8*)(Ar1 + k0);
#pragma unroll
        for (int fi = 0; fi < 8; fi++) {
            const bf16* Bp = Wh + (size_t)(fi * 16 + lm) * K + lq * 8 + k0;
            bf16x8 bv = *(const bf16x8*)Bp;
            acc[0][fi] = __builtin_amdgcn_mfma_f32_16x16x32_bf16(a0, bv, acc[0][fi], 0, 0, 0);
            acc[1][fi] = __builtin_amdgcn_mfma_f32_16x16x32_bf16(a1, bv, acc[1][fi], 0, 0, 0);
        }
    }

#pragma unroll
    for (int rb = 0; rb < 2; rb++) {
        int crow0 = m0 + rb * 16 + lq * 4;
        float ps[4] = {0.f, 0.f, 0.f, 0.f};
        float pd[4] = {0.f, 0.f, 0.f, 0.f};
#pragma unroll
        for (int fi = 0; fi < 8; fi++) {
            int col = head * 128 + fi * 16 + lm;
            float as = a_src[col], ad = a_dst[col];
#pragma unroll
            for (int r = 0; r < 4; r++) {
                float v = acc[rb][fi][r];
                ps[r] = fmaf(v, as, ps[r]);
                pd[r] = fmaf(v, ad, pd[r]);
                int cr = crow0 + r;
                if (cr < NN)
                    H[((size_t)g * NN + cr) * HIDD + col] = __float2bfloat16(v);
            }
        }
#pragma unroll
        for (int r = 0; r < 4; r++) {
            float a = ps[r], b = pd[r];
#pragma unroll
            for (int off = 1; off < 16; off <<= 1) {
                a += __shfl_xor(a, off);
                b += __shfl_xor(b, off);
            }
            if (lm == 0) {
                int cr = crow0 + r;
                if (cr < NN) {
                    als[((size_t)g * NN + cr) * 2 + head] = a;
                    ald[((size_t)g * NN + cr) * 2 + head] = b;
                }
            }
        }
    }
}

// ---------------- fused attention: softmax stats + per-edge record, wave per node ----------------
// rec[e] = {src_bits, alpha0, alpha1, pad}
__global__ __launch_bounds__(256) void att_kernel(const int* __restrict__ row_start,
                                                  const int* __restrict__ csr_src,
                                                  const float2* __restrict__ als2,
                                                  const float2* __restrict__ ald2,
                                                  float4* __restrict__ rec, int E) {
    int b = blockIdx.x;
    int g = b & 3;
    int wave = threadIdx.x >> 6, lane = threadIdx.x & 63;
    int n = (b >> 2) * 4 + wave;
    if (n >= NN) return;
    int start = row_start[n];
    int deg   = row_start[n + 1] - start;

    const float2* als = als2 + (size_t)g * NN;
    float2 ad = ald2[(size_t)g * NN + n];
    const int* Sr = csr_src + start;
    float4* Rr = rec + (size_t)g * E + start;

    float m0 = -1e30f, m1 = -1e30f;
    for (int i = lane; i < deg; i += 64) {
        float2 as = als[Sr[i]];
        m0 = fmaxf(m0, lrelu(as.x + ad.x));
        m1 = fmaxf(m1, lrelu(as.y + ad.y));
    }
#pragma unroll
    for (int off = 32; off; off >>= 1) {
        m0 = fmaxf(m0, __shfl_xor(m0, off));
        m1 = fmaxf(m1, __shfl_xor(m1, off));
    }
    float d0 = 0.f, d1 = 0.f;
    for (int i = lane; i < deg; i += 64) {
        float2 as = als[Sr[i]];
        d0 += __expf(lrelu(as.x + ad.x) - m0);
        d1 += __expf(lrelu(as.y + ad.y) - m1);
    }
#pragma unroll
    for (int off = 32; off; off >>= 1) {
        d0 += __shfl_xor(d0, off);
        d1 += __shfl_xor(d1, off);
    }
    float rd0 = 1.f / d0, rd1 = 1.f / d1;
    for (int i = lane; i < deg; i += 64) {
        int s = Sr[i];
        float2 as = als[s];
        float a0 = __expf(lrelu(as.x + ad.x) - m0) * rd0;
        float a1 = __expf(lrelu(as.y + ad.y) - m1) * rd1;
        Rr[i] = make_float4(__int_as_float(s), a0, a1, 0.f);
    }
}

// ---------------- aggregate + bias + LN + ReLU, one WAVE per (g,n) ----------------
// 2 edge-groups x 32 lanes; each lane owns 8 contiguous channels (uint4 load);
// group-fold + LN via shfl only — no LDS, no barriers.
template <typename OT>
__global__ __launch_bounds__(256) void node_kernel(const int* __restrict__ row_start,
                                                   const float4* __restrict__ rec,
                                                   const bf16* __restrict__ H,
                                                   const float* __restrict__ bias,
                                                   const float* __restrict__ gam,
                                                   const float* __restrict__ bet,
                                                   OT* __restrict__ out, int E) {
    int b = blockIdx.x;
    int g = b & 3;
    int wave = threadIdx.x >> 6, lane = threadIdx.x & 63;
    int n = (b >> 2) * 4 + wave;
    if (n >= NN) return;
    int grp = lane >> 5, lch = lane & 31;
    int hd_g = lch >> 4;
    int start = row_start[n];
    int deg   = row_start[n + 1] - start;

    const bf16*   Hg = H + (size_t)g * NN * HIDD;
    const float4* R  = rec + (size_t)g * E + start;

    float acc[8] = {0.f, 0.f, 0.f, 0.f, 0.f, 0.f, 0.f, 0.f};

#define EDGE_FMA(rr, qq)                                            \
    {                                                               \
        float wv = hd_g ? rr.z : rr.y;                              \
        acc[0] = fmaf(wv, __uint_as_float(qq.x << 16), acc[0]);     \
        acc[1] = fmaf(wv, __uint_as_float(qq.x & 0xffff0000u), acc[1]); \
        acc[2] = fmaf(wv, __uint_as_float(qq.y << 16), acc[2]);     \
        acc[3] = fmaf(wv, __uint_as_float(qq.y & 0xffff0000u), acc[3]); \
        acc[4] = fmaf(wv, __uint_as_float(qq.z << 16), acc[4]);     \
        acc[5] = fmaf(wv, __uint_as_float(qq.z & 0xffff0000u), acc[5]); \
        acc[6] = fmaf(wv, __uint_as_float(qq.w << 16), acc[6]);     \
        acc[7] = fmaf(wv, __uint_as_float(qq.w & 0xffff0000u), acc[7]); \
    }

    int i = grp;
    for (; i + 6 < deg; i += 8) {
        float4 r0 = R[i], r1 = R[i + 2], r2 = R[i + 4], r3 = R[i + 6];
        uint4 q0 = *(const uint4*)(Hg + (size_t)__float_as_int(r0.x) * HIDD + lch * 8);
        uint4 q1 = *(const uint4*)(Hg + (size_t)__float_as_int(r1.x) * HIDD + lch * 8);
        uint4 q2 = *(const uint4*)(Hg + (size_t)__float_as_int(r2.x) * HIDD + lch * 8);
        uint4 q3 = *(const uint4*)(Hg + (size_t)__float_as_int(r3.x) * HIDD + lch * 8);
        EDGE_FMA(r0, q0)
        EDGE_FMA(r1, q1)
        EDGE_FMA(r2, q2)
        EDGE_FMA(r3, q3)
    }
    for (; i < deg; i += 2) {
        float4 r0 = R[i];
        uint4 q0 = *(const uint4*)(Hg + (size_t)__float_as_int(r0.x) * HIDD + lch * 8);
        EDGE_FMA(r0, q0)
    }
#undef EDGE_FMA

    // fold group1 into group0 (after this all 64 lanes hold the full sums)
#pragma unroll
    for (int j = 0; j < 8; j++) acc[j] += __shfl_xor(acc[j], 32);

    // bias + LN over 256 channels: per-lane 8 ch, reduce across 32 lanes
    float4 bi0 = *(const float4*)(bias + lch * 8);
    float4 bi1 = *(const float4*)(bias + lch * 8 + 4);
    float v[8];
    v[0] = acc[0] + bi0.x; v[1] = acc[1] + bi0.y; v[2] = acc[2] + bi0.z; v[3] = acc[3] + bi0.w;
    v[4] = acc[4] + bi1.x; v[5] = acc[5] + bi1.y; v[6] = acc[6] + bi1.z; v[7] = acc[7] + bi1.w;

    float s1 = 0.f, s2 = 0.f;
#pragma unroll
    for (int j = 0; j < 8; j++) { s1 += v[j]; s2 += v[j] * v[j]; }
#pragma unroll
    for (int off = 16; off; off >>= 1) {
        s1 += __shfl_xor(s1, off);
        s2 += __shfl_xor(s2, off);
    }
    float mu  = s1 * (1.f / HIDD);
    float var = s2 * (1.f / HIDD) - mu * mu;
    float rs  = rsqrtf(var + 1e-5f);

    float4 ga0 = *(const float4*)(gam + lch * 8);
    float4 ga1 = *(const float4*)(gam + lch * 8 + 4);
    float4 be0 = *(const float4*)(bet + lch * 8);
    float4 be1 = *(const float4*)(bet + lch * 8 + 4);
    float gaf[8] = {ga0.x, ga0.y, ga0.z, ga0.w, ga1.x, ga1.y, ga1.z, ga1.w};
    float bef[8] = {be0.x, be0.y, be0.z, be0.w, be1.x, be1.y, be1.z, be1.w};

    float o[8];
#pragma unroll
    for (int j = 0; j < 8; j++)
        o[j] = fmaxf((v[j] - mu) * rs * gaf[j] + bef[j], 0.f);

    if (grp == 0) {
        size_t base = ((size_t)g * NN + n) * HIDD + lch * 8;
        if constexpr (sizeof(OT) == 2) {
            uint4 pk;
            pk.x = pack2(o[0], o[1]); pk.y = pack2(o[2], o[3]);
            pk.z = pack2(o[4], o[5]); pk.w = pack2(o[6], o[7]);
            *(uint4*)((bf16*)out + base) = pk;
        } else {
            *(float4*)((float*)out + base)     = make_float4(o[0], o[1], o[2], o[3]);
            *(float4*)((float*)out + base + 4) = make_float4(o[4], o[5], o[6], o[7]);
        }
    }
}

// ---------------- launch ----------------
extern "C" void kernel_launch(void* const* d_in, const int* in_sizes, int n_in,
                              void* d_out, int out_size, void* d_ws, size_t ws_size,
                              hipStream_t stream) {
    const float* feature = (const float*)d_in[0];
    const int*   ei      = (const int*)d_in[1];
    const float* W1      = (const float*)d_in[2];
    const float* a_src1  = (const float*)d_in[3];
    const float* a_dst1  = (const float*)d_in[4];
    const float* b1      = (const float*)d_in[5];
    const float* g1      = (const float*)d_in[6];
    const float* be1     = (const float*)d_in[7];
    const float* W2      = (const float*)d_in[8];
    const float* a_src2  = (const float*)d_in[9];
    const float* a_dst2  = (const float*)d_in[10];
    const float* b2      = (const float*)d_in[11];
    const float* g2      = (const float*)d_in[12];
    const float* be2     = (const float*)d_in[13];
    float* out = (float*)d_out;

    const int E = in_sizes[1] / 2;
    const int* srcv = ei;
    const int* dstv = ei + E;

    char* w = (char*)d_ws;
    auto alloc = [&](size_t bytes) -> char* {
        char* p = w;
        w += (bytes + 255) & ~(size_t)255;
        return p;
    };
    int*    counts    = (int*)alloc(sizeof(int) * NN);
    int*    row_start = (int*)alloc(sizeof(int) * (NN + 1));
    int*    cursor    = (int*)alloc(sizeof(int) * NN);
    int*    csr_src   = (int*)alloc(sizeof(int) * E);
    float*  als       = (float*)alloc(sizeof(float) * (size_t)BB * NN * 2);
    float*  ald       = (float*)alloc(sizeof(float) * (size_t)BB * NN * 2);
    float4* rec       = (float4*)alloc(sizeof(float4) * (size_t)BB * E);
    bf16*   featbf    = (bf16*)alloc(sizeof(bf16) * (size_t)BB * NN * DD);
    bf16*   h         = (bf16*)alloc(sizeof(bf16) * (size_t)BB * NN * HIDD);
    bf16*   x2        = (bf16*)alloc(sizeof(bf16) * (size_t)BB * NN * HIDD);
    bf16*   Wt        = (bf16*)alloc(sizeof(bf16) * HIDD * HIDD);

    // CSR build (shared by both layers, all graphs)
    zero_kernel<<<(NN + 255) / 256, 256, 0, stream>>>(counts, NN);
    hist_kernel<<<(E + 255) / 256, 256, 0, stream>>>(dstv, counts, E);
    scan_kernel<<<1, 1024, 0, stream>>>(counts, row_start, cursor);
    scatter_kernel<<<(E + 255) / 256, 256, 0, stream>>>(srcv, dstv, cursor, csr_src, E);

    int nblk = ((NN + 3) / 4) * 4;  // 4 nodes per block x 4 graphs interleaved => NN/4*4 blocks
    // grid: b in [0, 4*ceil(NN/4)); g = b&3, n = (b>>2)*4 + wave

    // Layer 1
    {
        int nf = BB * NN * DD;
        convert_kernel<<<(nf + 255) / 256, 256, 0, stream>>>(feature, featbf, nf);
    }
    convwt_kernel<<<(DD * HIDD + 255) / 256, 256, 0, stream>>>(W1, Wt, DD);
    gemm_kernel<DD><<<dim3((NN + 127) / 128, 2, BB), 256, 0, stream>>>(featbf, Wt, a_src1, a_dst1, h, als, ald);
    att_kernel<<<nblk, 256, 0, stream>>>(row_start, csr_src, (const float2*)als, (const float2*)ald, rec, E);
    node_kernel<bf16><<<nblk, 256, 0, stream>>>(row_start, rec, h, b1, g1, be1, x2, E);

    // Layer 2
    convwt_kernel<<<(HIDD * HIDD + 255) / 256, 256, 0, stream>>>(W2, Wt, HIDD);
    gemm_kernel<HIDD><<<dim3((NN + 127) / 128, 2, BB), 256, 0, stream>>>(x2, Wt, a_src2, a_dst2, h, als, ald);
    att_kernel<<<nblk, 256, 0, stream>>>(row_start, csr_src, (const float2*)als, (const float2*)ald, rec, E);
    node_kernel<float><<<nblk, 256, 0, stream>>>(row_start, rec, h, b2, g2, be2, out, E);
}